// Round 8
// baseline (695.233 us; speedup 1.0000x reference)
//
#include <hip/hip_runtime.h>
#include <hip/hip_bf16.h>
#include <stdint.h>

#define B_SZ 4
#define L_SEQ 2048
#define EMB 2048
#define NH 16
#define HD 128
#define BLROWS (B_SZ * L_SEQ)   // 8192
#define BK 32

typedef __bf16 bf16;
typedef __bf16 bf16x8 __attribute__((ext_vector_type(8)));
typedef __bf16 bf16x4 __attribute__((ext_vector_type(4)));
typedef float f32x4 __attribute__((ext_vector_type(4)));

#define MFMA16(A, Bv, C) __builtin_amdgcn_mfma_f32_16x16x32_bf16(A, Bv, C, 0, 0, 0)

__device__ __forceinline__ void gll16(bf16* l, const bf16* g) {
  __builtin_amdgcn_global_load_lds(
      (const __attribute__((address_space(1))) unsigned int*)g,
      (__attribute__((address_space(3))) unsigned int*)l, 16, 0, 0);
}

// ---------------- fp32 -> bf16 convert ----------------
__global__ __launch_bounds__(256) void f2b_kernel(const float* __restrict__ in,
                                                  bf16* __restrict__ out, int n4) {
  int i = blockIdx.x * blockDim.x + threadIdx.x;
  int stride = gridDim.x * blockDim.x;
  for (; i < n4; i += stride) {
    float4 v = ((const float4*)in)[i];
    bf16x4 o = {(bf16)v.x, (bf16)v.y, (bf16)v.z, (bf16)v.w};
    ((bf16x4*)out)[i] = o;
  }
}

// ---------------- 256x256 GEMM, BK=32, 3-stage counted-vmcnt pipeline -------
// (round-3 proven structure: 212 us @ 972 TF for QKV)
template <int EPI>
__global__ __launch_bounds__(512, 2) void gemm256(const bf16* __restrict__ A,
                                                  const bf16* __restrict__ Bm,
                                                  bf16* __restrict__ Cq,
                                                  bf16* __restrict__ Ck,
                                                  bf16* __restrict__ Cvt,
                                                  float* __restrict__ Cf,
                                                  int K) {
  __shared__ bf16 Abuf[3][256 * BK];
  __shared__ bf16 Bbuf[3][256 * BK];
  const int tid = threadIdx.x, lane = tid & 63, w = tid >> 6;
  const int wr = w >> 2, wc = w & 3;
  const int l15 = lane & 15;

  const int q8 = gridDim.x >> 3;
  const int wg = ((int)blockIdx.x & 7) * q8 + ((int)blockIdx.x >> 3);
  const int bm = (wg & 31) * 256;
  const int bn = (wg >> 5) * 256;
  const int NT = K / BK;

  const int idA0 = tid, idA1 = 512 + tid;
  const int ar0 = idA0 >> 2, ar1 = idA1 >> 2;
  const size_t aS0 = (size_t)(bm + ar0) * K + (((idA0 & 3) ^ ((ar0 >> 1) & 3)) * 8);
  const size_t aS1 = (size_t)(bm + ar1) * K + (((idA1 & 3) ^ ((ar1 >> 1) & 3)) * 8);
  const size_t bS0 = (size_t)(bn + ar0) * K + (((idA0 & 3) ^ ((ar0 >> 1) & 3)) * 8);
  const size_t bS1 = (size_t)(bn + ar1) * K + (((idA1 & 3) ^ ((ar1 >> 1) & 3)) * 8);
  const int ldsD0 = idA0 * 8, ldsD1 = idA1 * 8;

  const int eSw = ((lane >> 4) * 8) ^ (((l15 >> 1) & 3) << 3);
  int aoff[8], boff[4];
#pragma unroll
  for (int m = 0; m < 8; m++) aoff[m] = (wr * 128 + m * 16 + l15) * BK + eSw;
#pragma unroll
  for (int n = 0; n < 4; n++) boff[n] = (wc * 64 + n * 16 + l15) * BK + eSw;

  f32x4 acc[8][4] = {};

  gll16(&Abuf[0][ldsD0], A + aS0);
  gll16(&Bbuf[0][ldsD0], Bm + bS0);
  gll16(&Abuf[0][ldsD1], A + aS1);
  gll16(&Bbuf[0][ldsD1], Bm + bS1);
  gll16(&Abuf[1][ldsD0], A + aS0 + BK);
  gll16(&Bbuf[1][ldsD0], Bm + bS0 + BK);
  gll16(&Abuf[1][ldsD1], A + aS1 + BK);
  gll16(&Bbuf[1][ldsD1], Bm + bS1 + BK);
  asm volatile("s_waitcnt vmcnt(4)" ::: "memory");
  __builtin_amdgcn_s_barrier();
  asm volatile("" ::: "memory");

  int cur = 0, nxt = 2;
  for (int kt = 0; kt < NT; ++kt) {
    const bf16* __restrict__ Ab = Abuf[cur];
    const bf16* __restrict__ Bb = Bbuf[cur];
    const bool pre = (kt + 2 < NT);
    const size_t k2 = (size_t)(kt + 2) * BK;

    bf16x8 af[8], b0, b1;
#pragma unroll
    for (int m = 0; m < 8; m++) af[m] = *(const bf16x8*)&Ab[aoff[m]];
    b0 = *(const bf16x8*)&Bb[boff[0]];
    b1 = *(const bf16x8*)&Bb[boff[1]];
    if (pre) {
      gll16(&Abuf[nxt][ldsD0], A + aS0 + k2);
      gll16(&Bbuf[nxt][ldsD0], Bm + bS0 + k2);
    }
    asm volatile("s_waitcnt lgkmcnt(0)" ::: "memory");
    __builtin_amdgcn_sched_barrier(0);
    __builtin_amdgcn_s_setprio(1);
#pragma unroll
    for (int m = 0; m < 8; m++) acc[m][0] = MFMA16(af[m], b0, acc[m][0]);
#pragma unroll
    for (int m = 0; m < 8; m++) acc[m][1] = MFMA16(af[m], b1, acc[m][1]);
    __builtin_amdgcn_s_setprio(0);

    bf16x8 b2 = *(const bf16x8*)&Bb[boff[2]];
    bf16x8 b3 = *(const bf16x8*)&Bb[boff[3]];
    if (pre) {
      gll16(&Abuf[nxt][ldsD1], A + aS1 + k2);
      gll16(&Bbuf[nxt][ldsD1], Bm + bS1 + k2);
    }
    asm volatile("s_waitcnt lgkmcnt(0)" ::: "memory");
    __builtin_amdgcn_sched_barrier(0);
    __builtin_amdgcn_s_setprio(1);
#pragma unroll
    for (int m = 0; m < 8; m++) acc[m][2] = MFMA16(af[m], b2, acc[m][2]);
#pragma unroll
    for (int m = 0; m < 8; m++) acc[m][3] = MFMA16(af[m], b3, acc[m][3]);
    __builtin_amdgcn_s_setprio(0);

    if (kt < NT - 1) {
      if (pre)
        asm volatile("s_waitcnt vmcnt(4)" ::: "memory");
      else
        asm volatile("s_waitcnt vmcnt(0)" ::: "memory");
      __builtin_amdgcn_s_barrier();
      asm volatile("" ::: "memory");
    }
    cur = (cur == 2) ? 0 : cur + 1;
    nxt = (nxt == 2) ? 0 : nxt + 1;
  }

  const int grow0 = bm + wr * 128 + (lane >> 4) * 4;
  const int gcol0 = bn + wc * 64 + l15;
#pragma unroll
  for (int i = 0; i < 8; i++)
#pragma unroll
    for (int j = 0; j < 4; j++) {
      int grow = grow0 + i * 16;
      int gcol = gcol0 + j * 16;
      if (EPI == 1) {
#pragma unroll
        for (int r = 0; r < 4; r++)
          Cf[(size_t)(grow + r) * 2048 + gcol] = acc[i][j][r];
      } else {
        int mat = gcol >> 11, mcol = gcol & 2047;
        if (mat == 2) {
          int b = grow >> 11;
          bf16x4 pk = {(bf16)acc[i][j][0], (bf16)acc[i][j][1],
                       (bf16)acc[i][j][2], (bf16)acc[i][j][3]};
          *(bf16x4*)&Cvt[((size_t)(b * 2048 + mcol)) * 2048 + (grow & 2047)] = pk;
        } else {
          bf16* Cp = (mat == 0) ? Cq : Ck;
#pragma unroll
          for (int r = 0; r < 4; r++)
            Cp[(size_t)(grow + r) * 2048 + mcol] = (bf16)acc[i][j][r];
        }
      }
    }
}

// ---------------- fused RMSNorm + RoPE, in place ----------------
__global__ __launch_bounds__(256) void normrope_kernel(bf16* __restrict__ T,
                                                       const float* __restrict__ w,
                                                       const float* __restrict__ cs,
                                                       const float* __restrict__ sn) {
  int row = blockIdx.x * 4 + (threadIdx.x >> 6);
  int lane = threadIdx.x & 63;
  int bl = row >> 4;
  int h = row & 15;
  bf16* p = T + (size_t)bl * EMB + h * HD;
  float v1 = (float)p[lane];
  float v2 = (float)p[lane + 64];
  float ss = v1 * v1 + v2 * v2;
#pragma unroll
  for (int m = 32; m; m >>= 1) ss += __shfl_xor(ss, m, 64);
  float r = rsqrtf(ss * (1.0f / 128.0f) + 1e-6f);
  float n1 = v1 * r * w[lane];
  float n2 = v2 * r * w[lane + 64];
  float c = cs[(size_t)bl * 64 + lane];
  float s = sn[(size_t)bl * 64 + lane];
  p[lane]      = (bf16)(n1 * c - n2 * s);
  p[lane + 64] = (bf16)(n1 * s + n2 * c);
}

// ------- causal flash attention: bounded-exp + k-parity wave split ---------
// Block = 64 q-rows, 4 waves. Wave (qh=w&1, kp=w>>1): qh picks 32 q-rows
// (2 m-frags), kp picks k-tile parity. Per kt only matching-parity waves
// compute (wave-uniform); all waves co-stage. Partial O/lsum over disjoint
// k-sets add directly (bounded-exp has no running-max state). Epilogue:
// kp=1 waves dump O/lsum to LDS (reusing Ks/Vs), kp=0 add+divide+store.
__device__ __forceinline__ void stage_kv(bf16* Ksb, bf16* Vsb,
                                         const bf16* gK, const bf16* gV,
                                         int kt, int w, int lane) {
#pragma unroll
  for (int i = 0; i < 4; i++) {
    int ck = i * 256 + w * 64 + lane;
    int kr = ck >> 4, kc = ck & 15;
    gll16(&Ksb[ck * 8], gK + (size_t)(kt * 64 + kr) * EMB + ((kc ^ (kr & 7)) * 8));
    int dr = ck >> 3, vc = ck & 7;
    gll16(&Vsb[ck * 8], gV + (size_t)dr * L_SEQ + kt * 64 + ((vc ^ (dr & 7)) * 8));
  }
}

__global__ __launch_bounds__(256) void fattn_kernel(const bf16* __restrict__ Q,
                                                    const bf16* __restrict__ K,
                                                    const bf16* __restrict__ Vt,
                                                    bf16* __restrict__ AO) {
  __shared__ bf16 Ks[2][64 * 128];   // 32 KB (reused as f32 combine buf)
  __shared__ bf16 Vs[2][64 * 128];   // 32 KB (reused for lsum combine)
  __shared__ bf16 Ps[4 * 32 * 64];   // 16 KB (per-wave 32x64 P staging)
  const int tid = threadIdx.x, lane = tid & 63, w = tid >> 6;
  const int l15 = lane & 15;
  const int qh = w & 1, kp = w >> 1;

  int id = blockIdx.x + blockIdx.y * 32;
  int bh = id & 63;
  int qt = 31 - (id >> 6);           // heavy q-tiles first
  const int b = bh >> 4, h = bh & 15;
  const size_t base = (size_t)b * L_SEQ * EMB + h * HD;
  const bf16* gK = K + base;
  const bf16* gV = Vt + (size_t)(b * NH + h) * HD * L_SEQ;
  const int qrow0 = qt * 64 + qh * 32;   // wave's 32 q-rows

  const float a_ = 0.08838834764831845f * 1.4426950408889634f;  // scale*log2e
  const float b_ = 12.0f * 1.4426950408889634f;                 // bound*log2e

  bf16x8 qf[2][4];
#pragma unroll
  for (int mi = 0; mi < 2; mi++) {
    const bf16* qp = Q + base + (size_t)(qrow0 + mi * 16 + l15) * EMB + ((lane >> 4) * 8);
#pragma unroll
    for (int c = 0; c < 4; c++) qf[mi][c] = *(const bf16x8*)(qp + c * 32);
  }
  const bf16 one1 = (bf16)1.0f;
  const bf16x8 ones = {one1, one1, one1, one1, one1, one1, one1, one1};

  f32x4 O[2][8] = {};
  f32x4 lsum[2] = {};
  const int prow = (lane >> 4) * 4;
  bf16* myP = Ps + w * 2048;

  stage_kv(Ks[0], Vs[0], gK, gV, 0, w, lane);
  asm volatile("s_waitcnt vmcnt(0)" ::: "memory");
  __builtin_amdgcn_s_barrier();
  asm volatile("" ::: "memory");

  for (int kt = 0; kt <= qt; kt++) {
    const int cur = kt & 1;
    if (kt < qt) stage_kv(Ks[cur ^ 1], Vs[cur ^ 1], gK, gV, kt + 1, w, lane);

    if ((kt & 1) == kp) {   // wave-uniform parity gate
      // S = Q K^T : 16 shared kf reads feed 32 MFMA
      f32x4 S[2][4] = {};
      __builtin_amdgcn_s_setprio(1);
#pragma unroll
      for (int s = 0; s < 4; s++) {
        int row = s * 16 + l15;
#pragma unroll
        for (int c = 0; c < 4; c++) {
          int swc = (c * 4 + (lane >> 4)) ^ (row & 7);
          bf16x8 kf = *(const bf16x8*)&Ks[cur][row * 128 + swc * 8];
          S[0][s] = MFMA16(qf[0][c], kf, S[0][s]);
          S[1][s] = MFMA16(qf[1][c], kf, S[1][s]);
        }
      }
      __builtin_amdgcn_s_setprio(0);

      // bounded-exp P -> LDS (mask always; cheap cndmask)
#pragma unroll
      for (int mi = 0; mi < 2; mi++)
#pragma unroll
        for (int s = 0; s < 4; s++) {
          int kg = kt * 64 + s * 16 + l15;
#pragma unroll
          for (int r = 0; r < 4; r++) {
            int qg = qrow0 + mi * 16 + prow + r;
            float e = exp2f(S[mi][s][r] * a_ - b_);
            if (kg > qg) e = 0.f;
            int row = mi * 16 + prow + r;
            myP[(row * 64 + s * 16 + l15) ^ ((row & 7) << 3)] = (bf16)e;
          }
        }
      bf16x8 pf[2][2];
#pragma unroll
      for (int mi = 0; mi < 2; mi++)
#pragma unroll
        for (int kk = 0; kk < 2; kk++) {
          int row = mi * 16 + l15;
          int swc = (kk * 4 + (lane >> 4)) ^ (row & 7);
          pf[mi][kk] = *(const bf16x8*)&myP[row * 64 + swc * 8];
        }
      __builtin_amdgcn_s_setprio(1);
#pragma unroll
      for (int mi = 0; mi < 2; mi++) {
        lsum[mi] = MFMA16(pf[mi][0], ones, lsum[mi]);
        lsum[mi] = MFMA16(pf[mi][1], ones, lsum[mi]);
      }
#pragma unroll
      for (int ni = 0; ni < 8; ni++) {
#pragma unroll
        for (int kk = 0; kk < 2; kk++) {
          int drow = ni * 16 + l15;
          int swc = (kk * 4 + (lane >> 4)) ^ (drow & 7);
          bf16x8 vf = *(const bf16x8*)&Vs[cur][drow * 64 + swc * 8];
          O[0][ni] = MFMA16(pf[0][kk], vf, O[0][ni]);
          O[1][ni] = MFMA16(pf[1][kk], vf, O[1][ni]);
        }
      }
      __builtin_amdgcn_s_setprio(0);
    }

    asm volatile("s_waitcnt vmcnt(0)" ::: "memory");
    __builtin_amdgcn_s_barrier();
    asm volatile("" ::: "memory");
  }

  // ---- cross-parity combine (kp=1 -> LDS; kp=0 adds, divides, stores)
  __syncthreads();
  float* cO = (float*)Ks;            // [qh][32][128] f32 = 2 x 16 KB
  float* cL = (float*)Vs;            // [qh][32] f32
  if (kp == 1) {
#pragma unroll
    for (int mi = 0; mi < 2; mi++) {
#pragma unroll
      for (int ni = 0; ni < 8; ni++)
#pragma unroll
        for (int r = 0; r < 4; r++)
          cO[qh * 4096 + (mi * 16 + prow + r) * 128 + ni * 16 + l15] = O[mi][ni][r];
      if (l15 == 0)
#pragma unroll
        for (int r = 0; r < 4; r++) cL[qh * 32 + mi * 16 + prow + r] = lsum[mi][r];
    }
  }
  __syncthreads();
  if (kp == 0) {
#pragma unroll
    for (int mi = 0; mi < 2; mi++) {
      f32x4 lt;
#pragma unroll
      for (int r = 0; r < 4; r++)
        lt[r] = lsum[mi][r] + cL[qh * 32 + mi * 16 + prow + r];
#pragma unroll
      for (int ni = 0; ni < 8; ni++)
#pragma unroll
        for (int r = 0; r < 4; r++) {
          float o = (O[mi][ni][r] +
                     cO[qh * 4096 + (mi * 16 + prow + r) * 128 + ni * 16 + l15]) / lt[r];
          int grow = qrow0 + mi * 16 + prow + r;
          AO[(size_t)(b * L_SEQ + grow) * EMB + h * HD + ni * 16 + l15] = (bf16)o;
        }
    }
  }
}

extern "C" void kernel_launch(void* const* d_in, const int* in_sizes, int n_in,
                              void* d_out, int out_size, void* d_ws, size_t ws_size,
                              hipStream_t stream) {
  const float* x = (const float*)d_in[0];
  const float* cosp = (const float*)d_in[2];
  const float* sinp = (const float*)d_in[3];
  const float* Wq = (const float*)d_in[4];
  const float* Wk = (const float*)d_in[5];
  const float* Wv = (const float*)d_in[6];
  const float* Wo = (const float*)d_in[7];
  const float* qw = (const float*)d_in[8];
  const float* kw = (const float*)d_in[9];

  const size_t ACT = (size_t)BLROWS * EMB * sizeof(bf16);
  const size_t WGT = (size_t)EMB * EMB * sizeof(bf16);
  char* ws = (char*)d_ws;
  bf16* xb    = (bf16*)ws;          ws += ACT;
  bf16* WQKVb = (bf16*)ws;          ws += 3 * WGT;
  bf16* Wob   = (bf16*)ws;          ws += WGT;
  bf16* Qb    = (bf16*)ws;          ws += ACT;
  bf16* Kb    = (bf16*)ws;          ws += ACT;
  bf16* Vtb   = (bf16*)ws;          ws += ACT;
  bf16* AOb   = (bf16*)ws;          ws += ACT;

  f2b_kernel<<<2048, 256, 0, stream>>>(x, xb, BLROWS * EMB / 4);
  f2b_kernel<<<1024, 256, 0, stream>>>(Wq, WQKVb, EMB * EMB / 4);
  f2b_kernel<<<1024, 256, 0, stream>>>(Wk, WQKVb + (size_t)EMB * EMB, EMB * EMB / 4);
  f2b_kernel<<<1024, 256, 0, stream>>>(Wv, WQKVb + 2 * (size_t)EMB * EMB, EMB * EMB / 4);
  f2b_kernel<<<1024, 256, 0, stream>>>(Wo, Wob, EMB * EMB / 4);

  gemm256<0><<<768, 512, 0, stream>>>(xb, WQKVb, Qb, Kb, Vtb, nullptr, EMB);

  normrope_kernel<<<BLROWS * NH / 4, 256, 0, stream>>>(Qb, qw, cosp, sinp);
  normrope_kernel<<<BLROWS * NH / 4, 256, 0, stream>>>(Kb, kw, cosp, sinp);

  fattn_kernel<<<dim3(32, B_SZ * NH), 256, 0, stream>>>(Qb, Kb, Vtb, AOb);

  gemm256<1><<<256, 512, 0, stream>>>(AOb, Wob, nullptr, nullptr, nullptr,
                                      (float*)d_out, EMB);
}

// Round 9
// 478.768 us; speedup vs baseline: 1.4521x; 1.4521x over previous
//
#include <hip/hip_runtime.h>
#include <hip/hip_bf16.h>
#include <stdint.h>

#define B_SZ 4
#define L_SEQ 2048
#define EMB 2048
#define NH 16
#define HD 128
#define BLROWS (B_SZ * L_SEQ)   // 8192
#define BK 32

typedef __bf16 bf16;
typedef __bf16 bf16x8 __attribute__((ext_vector_type(8)));
typedef __bf16 bf16x4 __attribute__((ext_vector_type(4)));
typedef float f32x4 __attribute__((ext_vector_type(4)));

#define MFMA16(A, Bv, C) __builtin_amdgcn_mfma_f32_16x16x32_bf16(A, Bv, C, 0, 0, 0)

__device__ __forceinline__ void gll16(bf16* l, const bf16* g) {
  __builtin_amdgcn_global_load_lds(
      (const __attribute__((address_space(1))) unsigned int*)g,
      (__attribute__((address_space(3))) unsigned int*)l, 16, 0, 0);
}

// ---------------- fp32 -> bf16 convert (x) ----------------
__global__ __launch_bounds__(256) void f2b_kernel(const float* __restrict__ in,
                                                  bf16* __restrict__ out, int n4) {
  int i = blockIdx.x * blockDim.x + threadIdx.x;
  int stride = gridDim.x * blockDim.x;
  for (; i < n4; i += stride) {
    float4 v = ((const float4*)in)[i];
    bf16x4 o = {(bf16)v.x, (bf16)v.y, (bf16)v.z, (bf16)v.w};
    ((bf16x4*)out)[i] = o;
  }
}

// ---------------- fused weight conversions (4 tensors, one launch) ---------
__global__ __launch_bounds__(256) void f2bW_kernel(const float* __restrict__ w0,
                                                   const float* __restrict__ w1,
                                                   const float* __restrict__ w2,
                                                   const float* __restrict__ w3,
                                                   bf16* __restrict__ o0,
                                                   bf16* __restrict__ o1,
                                                   bf16* __restrict__ o2,
                                                   bf16* __restrict__ o3, int n4) {
  const float* in = (blockIdx.y == 0) ? w0 : (blockIdx.y == 1) ? w1
                    : (blockIdx.y == 2) ? w2 : w3;
  bf16* out = (blockIdx.y == 0) ? o0 : (blockIdx.y == 1) ? o1
              : (blockIdx.y == 2) ? o2 : o3;
  int i = blockIdx.x * blockDim.x + threadIdx.x;
  int stride = gridDim.x * blockDim.x;
  for (; i < n4; i += stride) {
    float4 v = ((const float4*)in)[i];
    bf16x4 o = {(bf16)v.x, (bf16)v.y, (bf16)v.z, (bf16)v.w};
    ((bf16x4*)out)[i] = o;
  }
}

// ------- 256xBNT GEMM, BK=32, 3-stage counted-vmcnt pipeline ---------------
// BNT=256: QKV fused epilogue (EPI 0), 1 block/CU. BNT=128: f32 out (EPI 1),
// 72 KB LDS -> 2 blocks/CU for the latency-bound out-projection.
template <int EPI, int BNT>
__global__ __launch_bounds__(512, 2) void gemm256(const bf16* __restrict__ A,
                                                  const bf16* __restrict__ Bm,
                                                  bf16* __restrict__ Cq,
                                                  bf16* __restrict__ Ck,
                                                  bf16* __restrict__ Cvt,
                                                  float* __restrict__ Cf,
                                                  int K) {
  constexpr int NB = BNT / 64;             // B n-frags per wave
  __shared__ bf16 Abuf[3][256 * BK];
  __shared__ bf16 Bbuf[3][BNT * BK];
  const int tid = threadIdx.x, lane = tid & 63, w = tid >> 6;
  const int wr = w >> 2, wc = w & 3;
  const int l15 = lane & 15;

  const int q8 = gridDim.x >> 3;
  const int wg = ((int)blockIdx.x & 7) * q8 + ((int)blockIdx.x >> 3);
  const int nbm = 32;                       // 8192/256
  const int bm = (wg & (nbm - 1)) * 256;
  const int bn = (wg / nbm) * BNT;
  const int NT = K / BK;

  const int idA0 = tid, idA1 = 512 + tid;
  const int ar0 = idA0 >> 2, ar1 = idA1 >> 2;
  const size_t aS0 = (size_t)(bm + ar0) * K + (((idA0 & 3) ^ ((ar0 >> 1) & 3)) * 8);
  const size_t aS1 = (size_t)(bm + ar1) * K + (((idA1 & 3) ^ ((ar1 >> 1) & 3)) * 8);
  const size_t bS0 = (size_t)(bn + ar0) * K + (((idA0 & 3) ^ ((ar0 >> 1) & 3)) * 8);
  const size_t bS1 = (size_t)(bn + ar1) * K + (((idA1 & 3) ^ ((ar1 >> 1) & 3)) * 8);
  const int ldsD0 = idA0 * 8, ldsD1 = idA1 * 8;

  const int eSw = ((lane >> 4) * 8) ^ (((l15 >> 1) & 3) << 3);
  int aoff[8], boff[NB];
#pragma unroll
  for (int m = 0; m < 8; m++) aoff[m] = (wr * 128 + m * 16 + l15) * BK + eSw;
#pragma unroll
  for (int n = 0; n < NB; n++) boff[n] = (wc * (BNT / 4) + n * 16 + l15) * BK + eSw;

  f32x4 acc[8][NB] = {};

  // prologue: stage tiles 0,1
  gll16(&Abuf[0][ldsD0], A + aS0);
  gll16(&Bbuf[0][ldsD0], Bm + bS0);
  gll16(&Abuf[0][ldsD1], A + aS1);
  if constexpr (BNT == 256) gll16(&Bbuf[0][ldsD1], Bm + bS1);
  gll16(&Abuf[1][ldsD0], A + aS0 + BK);
  gll16(&Bbuf[1][ldsD0], Bm + bS0 + BK);
  gll16(&Abuf[1][ldsD1], A + aS1 + BK);
  if constexpr (BNT == 256) gll16(&Bbuf[1][ldsD1], Bm + bS1 + BK);
  if constexpr (BNT == 256)
    asm volatile("s_waitcnt vmcnt(4)" ::: "memory");
  else
    asm volatile("s_waitcnt vmcnt(3)" ::: "memory");
  __builtin_amdgcn_s_barrier();
  asm volatile("" ::: "memory");

  int cur = 0, nxt = 2;
  for (int kt = 0; kt < NT; ++kt) {
    const bf16* __restrict__ Ab = Abuf[cur];
    const bf16* __restrict__ Bb = Bbuf[cur];
    const bool pre = (kt + 2 < NT);
    const size_t k2 = (size_t)(kt + 2) * BK;

    bf16x8 af[8], bq[NB];
#pragma unroll
    for (int m = 0; m < 8; m++) af[m] = *(const bf16x8*)&Ab[aoff[m]];
    bq[0] = *(const bf16x8*)&Bb[boff[0]];
    if constexpr (NB > 2) bq[1] = *(const bf16x8*)&Bb[boff[1]];
    if (pre) {
      gll16(&Abuf[nxt][ldsD0], A + aS0 + k2);
      gll16(&Bbuf[nxt][ldsD0], Bm + bS0 + k2);
    }
    asm volatile("s_waitcnt lgkmcnt(0)" ::: "memory");
    __builtin_amdgcn_sched_barrier(0);
    __builtin_amdgcn_s_setprio(1);
#pragma unroll
    for (int m = 0; m < 8; m++) acc[m][0] = MFMA16(af[m], bq[0], acc[m][0]);
    if constexpr (NB > 2) {
#pragma unroll
      for (int m = 0; m < 8; m++) acc[m][1] = MFMA16(af[m], bq[1], acc[m][1]);
    }
    __builtin_amdgcn_s_setprio(0);

    constexpr int n2 = (NB > 2) ? 2 : 1;
    bf16x8 b2 = *(const bf16x8*)&Bb[boff[n2]];
    bf16x8 b3;
    if constexpr (NB > 2) b3 = *(const bf16x8*)&Bb[boff[3]];
    if (pre) {
      gll16(&Abuf[nxt][ldsD1], A + aS1 + k2);
      if constexpr (BNT == 256) gll16(&Bbuf[nxt][ldsD1], Bm + bS1 + k2);
    }
    asm volatile("s_waitcnt lgkmcnt(0)" ::: "memory");
    __builtin_amdgcn_sched_barrier(0);
    __builtin_amdgcn_s_setprio(1);
#pragma unroll
    for (int m = 0; m < 8; m++) acc[m][n2] = MFMA16(af[m], b2, acc[m][n2]);
    if constexpr (NB > 2) {
#pragma unroll
      for (int m = 0; m < 8; m++) acc[m][3] = MFMA16(af[m], b3, acc[m][3]);
    }
    __builtin_amdgcn_s_setprio(0);

    if (kt < NT - 1) {
      if (pre) {
        if constexpr (BNT == 256)
          asm volatile("s_waitcnt vmcnt(4)" ::: "memory");
        else
          asm volatile("s_waitcnt vmcnt(3)" ::: "memory");
      } else {
        asm volatile("s_waitcnt vmcnt(0)" ::: "memory");
      }
      __builtin_amdgcn_s_barrier();
      asm volatile("" ::: "memory");
    }
    cur = (cur == 2) ? 0 : cur + 1;
    nxt = (nxt == 2) ? 0 : nxt + 1;
  }

  const int grow0 = bm + wr * 128 + (lane >> 4) * 4;
  const int gcol0 = bn + wc * (BNT / 4) + l15;
#pragma unroll
  for (int i = 0; i < 8; i++)
#pragma unroll
    for (int j = 0; j < NB; j++) {
      int grow = grow0 + i * 16;
      int gcol = gcol0 + j * 16;
      if (EPI == 1) {
#pragma unroll
        for (int r = 0; r < 4; r++)
          Cf[(size_t)(grow + r) * 2048 + gcol] = acc[i][j][r];
      } else {
        int mat = gcol >> 11, mcol = gcol & 2047;
        if (mat == 2) {
          int b = grow >> 11;
          bf16x4 pk = {(bf16)acc[i][j][0], (bf16)acc[i][j][1],
                       (bf16)acc[i][j][2], (bf16)acc[i][j][3]};
          *(bf16x4*)&Cvt[((size_t)(b * 2048 + mcol)) * 2048 + (grow & 2047)] = pk;
        } else {
          bf16* Cp = (mat == 0) ? Cq : Ck;
#pragma unroll
          for (int r = 0; r < 4; r++)
            Cp[(size_t)(grow + r) * 2048 + mcol] = (bf16)acc[i][j][r];
        }
      }
    }
}

// ---------------- fused RMSNorm + RoPE for Q and K, one launch -------------
__global__ __launch_bounds__(256) void normrope2_kernel(bf16* __restrict__ Tq,
                                                        bf16* __restrict__ Tk,
                                                        const float* __restrict__ wq,
                                                        const float* __restrict__ wk,
                                                        const float* __restrict__ cs,
                                                        const float* __restrict__ sn) {
  bf16* T = blockIdx.y ? Tk : Tq;
  const float* w = blockIdx.y ? wk : wq;
  int row = blockIdx.x * 4 + (threadIdx.x >> 6);
  int lane = threadIdx.x & 63;
  int bl = row >> 4;
  int h = row & 15;
  bf16* p = T + (size_t)bl * EMB + h * HD;
  float v1 = (float)p[lane];
  float v2 = (float)p[lane + 64];
  float ss = v1 * v1 + v2 * v2;
#pragma unroll
  for (int m = 32; m; m >>= 1) ss += __shfl_xor(ss, m, 64);
  float r = rsqrtf(ss * (1.0f / 128.0f) + 1e-6f);
  float n1 = v1 * r * w[lane];
  float n2 = v2 * r * w[lane + 64];
  float c = cs[(size_t)bl * 64 + lane];
  float s = sn[(size_t)bl * 64 + lane];
  p[lane]      = (bf16)(n1 * c - n2 * s);
  p[lane + 64] = (bf16)(n1 * s + n2 * c);
}

// ---------------- causal flash attention (round-4 proven version) ----------
__device__ __forceinline__ void stage_kv(bf16* Ksb, bf16* Vsb,
                                         const bf16* gK, const bf16* gV,
                                         int kt, int w, int lane) {
#pragma unroll
  for (int i = 0; i < 4; i++) {
    int ck = i * 256 + w * 64 + lane;
    int kr = ck >> 4, kc = ck & 15;
    gll16(&Ksb[ck * 8], gK + (size_t)(kt * 64 + kr) * EMB + ((kc ^ (kr & 7)) * 8));
    int dr = ck >> 3, vc = ck & 7;
    gll16(&Vsb[ck * 8], gV + (size_t)dr * L_SEQ + kt * 64 + ((vc ^ (dr & 7)) * 8));
  }
}

__global__ __launch_bounds__(256) void fattn_kernel(const bf16* __restrict__ Q,
                                                    const bf16* __restrict__ K,
                                                    const bf16* __restrict__ Vt,
                                                    bf16* __restrict__ AO) {
  __shared__ bf16 Ks[2][64 * 128];
  __shared__ bf16 Vs[2][64 * 128];
  __shared__ bf16 Ps[4 * 16 * 64];
  const int tid = threadIdx.x, lane = tid & 63, w = tid >> 6;

  int id = blockIdx.x + blockIdx.y * 32;
  int bh = id & 63;
  int qt = 31 - (id >> 6);
  const int b = bh >> 4, h = bh & 15;
  const size_t base = (size_t)b * L_SEQ * EMB + h * HD;
  const bf16* gK = K + base;
  const bf16* gV = Vt + (size_t)(b * NH + h) * HD * L_SEQ;
  const int qrow0 = qt * 64 + w * 16;

  const float a_ = 0.08838834764831845f * 1.4426950408889634f;
  const float b_ = 12.0f * 1.4426950408889634f;

  bf16x8 qf[4];
  {
    const bf16* qp = Q + base + (size_t)(qrow0 + (lane & 15)) * EMB + ((lane >> 4) * 8);
#pragma unroll
    for (int c = 0; c < 4; c++) qf[c] = *(const bf16x8*)(qp + c * 32);
  }
  const bf16 one1 = (bf16)1.0f;
  const bf16x8 ones = {one1, one1, one1, one1, one1, one1, one1, one1};

  f32x4 O[8] = {};
  f32x4 lsum = {0.f, 0.f, 0.f, 0.f};
  const int qg0 = qrow0 + (lane >> 4) * 4;
  bf16* myP = Ps + w * 1024;

  stage_kv(Ks[0], Vs[0], gK, gV, 0, w, lane);
  asm volatile("s_waitcnt vmcnt(0)" ::: "memory");
  __builtin_amdgcn_s_barrier();
  asm volatile("" ::: "memory");

  for (int kt = 0; kt <= qt; kt++) {
    const int cur = kt & 1;
    if (kt < qt) stage_kv(Ks[cur ^ 1], Vs[cur ^ 1], gK, gV, kt + 1, w, lane);

    f32x4 S[4] = {};
    __builtin_amdgcn_s_setprio(1);
#pragma unroll
    for (int s = 0; s < 4; s++) {
      int row = s * 16 + (lane & 15);
#pragma unroll
      for (int c = 0; c < 4; c++) {
        int swc = (c * 4 + (lane >> 4)) ^ (row & 7);
        bf16x8 kf = *(const bf16x8*)&Ks[cur][row * 128 + swc * 8];
        S[s] = MFMA16(qf[c], kf, S[s]);
      }
    }
    __builtin_amdgcn_s_setprio(0);

    const bool diag = (kt == qt);
    const int prow = (lane >> 4) * 4;
#pragma unroll
    for (int s = 0; s < 4; s++) {
      int kg = kt * 64 + s * 16 + (lane & 15);
#pragma unroll
      for (int r = 0; r < 4; r++) {
        float e = exp2f(S[s][r] * a_ - b_);
        if (diag && kg > qg0 + r) e = 0.f;
        int row = prow + r;
        myP[(row * 64 + s * 16 + (lane & 15)) ^ ((row & 7) << 3)] = (bf16)e;
      }
    }
    bf16x8 pf[2];
#pragma unroll
    for (int kk = 0; kk < 2; kk++) {
      int row = lane & 15;
      int swc = (kk * 4 + (lane >> 4)) ^ (row & 7);
      pf[kk] = *(const bf16x8*)&myP[row * 64 + swc * 8];
    }
    __builtin_amdgcn_s_setprio(1);
    lsum = MFMA16(pf[0], ones, lsum);
    lsum = MFMA16(pf[1], ones, lsum);
#pragma unroll
    for (int ni = 0; ni < 8; ni++) {
#pragma unroll
      for (int kk = 0; kk < 2; kk++) {
        int drow = ni * 16 + (lane & 15);
        int swc = (kk * 4 + (lane >> 4)) ^ (drow & 7);
        bf16x8 vf = *(const bf16x8*)&Vs[cur][drow * 64 + swc * 8];
        O[ni] = MFMA16(pf[kk], vf, O[ni]);
      }
    }
    __builtin_amdgcn_s_setprio(0);

    asm volatile("s_waitcnt vmcnt(0)" ::: "memory");
    __builtin_amdgcn_s_barrier();
    asm volatile("" ::: "memory");
  }

#pragma unroll
  for (int ni = 0; ni < 8; ni++) {
#pragma unroll
    for (int r = 0; r < 4; r++) {
      float o = O[ni][r] / lsum[r];
      AO[(size_t)(b * L_SEQ + qg0 + r) * EMB + h * HD + ni * 16 + (lane & 15)] = (bf16)o;
    }
  }
}

extern "C" void kernel_launch(void* const* d_in, const int* in_sizes, int n_in,
                              void* d_out, int out_size, void* d_ws, size_t ws_size,
                              hipStream_t stream) {
  const float* x = (const float*)d_in[0];
  const float* cosp = (const float*)d_in[2];
  const float* sinp = (const float*)d_in[3];
  const float* Wq = (const float*)d_in[4];
  const float* Wk = (const float*)d_in[5];
  const float* Wv = (const float*)d_in[6];
  const float* Wo = (const float*)d_in[7];
  const float* qw = (const float*)d_in[8];
  const float* kw = (const float*)d_in[9];

  const size_t ACT = (size_t)BLROWS * EMB * sizeof(bf16);
  const size_t WGT = (size_t)EMB * EMB * sizeof(bf16);
  char* ws = (char*)d_ws;
  bf16* xb    = (bf16*)ws;          ws += ACT;
  bf16* WQKVb = (bf16*)ws;          ws += 3 * WGT;
  bf16* Wob   = (bf16*)ws;          ws += WGT;
  bf16* Qb    = (bf16*)ws;          ws += ACT;
  bf16* Kb    = (bf16*)ws;          ws += ACT;
  bf16* Vtb   = (bf16*)ws;          ws += ACT;
  bf16* AOb   = (bf16*)ws;          ws += ACT;

  f2b_kernel<<<2048, 256, 0, stream>>>(x, xb, BLROWS * EMB / 4);
  f2bW_kernel<<<dim3(512, 4), 256, 0, stream>>>(
      Wq, Wk, Wv, Wo, WQKVb, WQKVb + (size_t)EMB * EMB,
      WQKVb + 2 * (size_t)EMB * EMB, Wob, EMB * EMB / 4);

  gemm256<0, 256><<<768, 512, 0, stream>>>(xb, WQKVb, Qb, Kb, Vtb, nullptr, EMB);

  normrope2_kernel<<<dim3(BLROWS * NH / 4, 2), 256, 0, stream>>>(Qb, Kb, qw, kw,
                                                                 cosp, sinp);

  fattn_kernel<<<dim3(32, B_SZ * NH), 256, 0, stream>>>(Qb, Kb, Vtb, AOb);

  gemm256<1, 128><<<512, 512, 0, stream>>>(AOb, Wob, nullptr, nullptr, nullptr,
                                           (float*)d_out, EMB);
}